// Round 5
// baseline (252.206 us; speedup 1.0000x reference)
//
#include <hip/hip_runtime.h>
#include <hip/hip_cooperative_groups.h>
#include <math.h>

namespace cg = cooperative_groups;

#define BB 4
#define NN 4096
#define TPB 256            // 4 waves per block
#define IPT 8              // i-points per thread
#define IBLK (TPB * IPT)   // 2048 i-points per block
#define ITILES (NN / IBLK) // 2
#define JCHUNK 128
#define NJC (NN / JCHUNK)  // 32
#define NBLK (BB * 2 * ITILES * NJC)       // 512
#define NI (2 * BB * NN)   // 32768 total (b,dir,i) slots
#define PART_BYTES ((size_t)NJC * NI * 4)  // 4 MB
#define WS_NEEDED (PART_BYTES + 512)

// ---- shared inner routine: compute per-(jc,slot) partial min-of-d^2 ----
// d^2(i,j) = |p_i|^2 - 2*(p_i.q_j - 0.5|q_j|^2).  Track max over j of
// s_j = p.q + w (w = -0.5|q|^2 in the LDS float4's .w): 3 fma + 1 max/pair.
__device__ __forceinline__ void min_phase(
    const float* __restrict__ pc1, const float* __restrict__ pc2,
    float* __restrict__ part, float4* sj) {
    int bid = blockIdx.x;
    int jc    = bid & (NJC - 1);    bid >>= 5;
    int itile = bid & (ITILES - 1); bid >>= 1;
    int dir   = bid & 1;            bid >>= 1;
    int b     = bid;

    const float* selfc  = (dir == 0) ? pc1 : pc2;
    const float* otherc = (dir == 0) ? pc2 : pc1;

    const float4* src4 =
        (const float4*)(otherc + (size_t)b * NN * 3 + (size_t)jc * JCHUNK * 3);
    if (threadIdx.x < JCHUNK / 4) {
        int t = threadIdx.x;
        float4 f0 = src4[3 * t + 0];
        float4 f1 = src4[3 * t + 1];
        float4 f2 = src4[3 * t + 2];
        float x0 = f0.x, y0 = f0.y, z0 = f0.z;
        float x1 = f0.w, y1 = f1.x, z1 = f1.y;
        float x2 = f1.z, y2 = f1.w, z2 = f2.x;
        float x3 = f2.y, y3 = f2.z, z3 = f2.w;
        sj[4 * t + 0] = make_float4(x0, y0, z0, -0.5f * (x0 * x0 + y0 * y0 + z0 * z0));
        sj[4 * t + 1] = make_float4(x1, y1, z1, -0.5f * (x1 * x1 + y1 * y1 + z1 * z1));
        sj[4 * t + 2] = make_float4(x2, y2, z2, -0.5f * (x2 * x2 + y2 * y2 + z2 * z2));
        sj[4 * t + 3] = make_float4(x3, y3, z3, -0.5f * (x3 * x3 + y3 * y3 + z3 * z3));
    }

    float px[IPT], py[IPT], pz[IPT], pp[IPT], m[IPT];
    const float* pbase = selfc + (size_t)b * NN * 3 +
                         (size_t)(itile * IBLK + threadIdx.x) * 3;
#pragma unroll
    for (int r = 0; r < IPT; ++r) {
        const float* p = pbase + (size_t)r * TPB * 3;
        px[r] = p[0]; py[r] = p[1]; pz[r] = p[2];
        pp[r] = px[r] * px[r] + py[r] * py[r] + pz[r] * pz[r];
        m[r] = -INFINITY;
    }
    __syncthreads();

#pragma unroll 2
    for (int j = 0; j < JCHUNK; ++j) {
        float4 q = sj[j];
#pragma unroll
        for (int r = 0; r < IPT; ++r) {
            float t = fmaf(px[r], q.x, q.w);
            t = fmaf(py[r], q.y, t);
            t = fmaf(pz[r], q.z, t);
            m[r] = fmaxf(m[r], t);
        }
    }

    int slot0 = (b * 2 + dir) * NN + itile * IBLK + threadIdx.x;
#pragma unroll
    for (int r = 0; r < IPT; ++r) {
        float d2 = fmaxf(0.f, fmaf(-2.f, m[r], pp[r]));
        part[(size_t)jc * NI + slot0 + r * TPB] = d2;  // coalesced
    }
}

// ---------------- fused cooperative kernel: 1 graph node ----------------
__global__ __launch_bounds__(TPB) void chamfer_fused_kernel(
    const float* __restrict__ pc1, const float* __restrict__ pc2,
    float* __restrict__ part, float* __restrict__ partial,
    float* __restrict__ out) {
    __shared__ float4 sj[JCHUNK];
    __shared__ float wsum[4];

    min_phase(pc1, pc2, part, sj);

    __threadfence();
    cg::this_grid().sync();

    // phase 2: 128 blocks, min over NJC chunks + sqrt + block sum
    if (blockIdx.x < NI / TPB) {
        int g = blockIdx.x * TPB + threadIdx.x;
        float m = part[g];
#pragma unroll
        for (int c = 1; c < NJC; ++c) m = fminf(m, part[(size_t)c * NI + g]);
        float s = sqrtf(fmaxf(m, 0.f));
        for (int off = 32; off > 0; off >>= 1) s += __shfl_down(s, off, 64);
        int wave = threadIdx.x >> 6;
        if ((threadIdx.x & 63) == 0) wsum[wave] = s;
        __syncthreads();
        if (threadIdx.x == 0)
            partial[blockIdx.x] = wsum[0] + wsum[1] + wsum[2] + wsum[3];
    }

    __threadfence();
    cg::this_grid().sync();

    // phase 3: block 0 sums the 128 partials and writes the scalar
    if (blockIdx.x == 0) {
        float s = (threadIdx.x < NI / TPB) ? partial[threadIdx.x] : 0.f;
        for (int off = 32; off > 0; off >>= 1) s += __shfl_down(s, off, 64);
        __syncthreads();  // wsum reused
        int wave = threadIdx.x >> 6;
        if ((threadIdx.x & 63) == 0) wsum[wave] = s;
        __syncthreads();
        if (threadIdx.x == 0)
            out[0] = (wsum[0] + wsum[1]) * (1.0f / (float)NI);
    }
}

// ---------------- fallback (non-cooperative) path ----------------
__global__ __launch_bounds__(TPB) void chamfer_min_kernel(
    const float* __restrict__ pc1, const float* __restrict__ pc2,
    float* __restrict__ part) {
    __shared__ float4 sj[JCHUNK];
    min_phase(pc1, pc2, part, sj);
}

__global__ __launch_bounds__(256) void chamfer_reduce_kernel(
    const float* __restrict__ part, float* __restrict__ out) {
    int g = blockIdx.x * 256 + threadIdx.x;
    float m = part[g];
#pragma unroll
    for (int c = 1; c < NJC; ++c) m = fminf(m, part[(size_t)c * NI + g]);
    float s = sqrtf(fmaxf(m, 0.f));
    for (int off = 32; off > 0; off >>= 1) s += __shfl_down(s, off, 64);
    __shared__ float wsum[4];
    int wave = threadIdx.x >> 6;
    if ((threadIdx.x & 63) == 0) wsum[wave] = s;
    __syncthreads();
    if (threadIdx.x == 0) {
        float tot = wsum[0] + wsum[1] + wsum[2] + wsum[3];
        atomicAdd(out, tot * (1.0f / (float)NI));
    }
}

extern "C" void kernel_launch(void* const* d_in, const int* in_sizes, int n_in,
                              void* d_out, int out_size, void* d_ws, size_t ws_size,
                              hipStream_t stream) {
    const float* pc1 = (const float*)d_in[0];
    const float* pc2 = (const float*)d_in[1];
    float* out = (float*)d_out;
    float* part = (float*)d_ws;
    float* partial = (float*)((char*)d_ws + PART_BYTES);

    bool coop_ok = false;
    if (ws_size >= WS_NEEDED) {
        void* args[] = {(void*)&pc1, (void*)&pc2, (void*)&part,
                        (void*)&partial, (void*)&out};
        hipError_t e = hipLaunchCooperativeKernel(
            (const void*)chamfer_fused_kernel, dim3(NBLK), dim3(TPB), args, 0,
            stream);
        coop_ok = (e == hipSuccess);
    }
    if (!coop_ok) {
        // proven 3-dispatch fallback
        hipMemsetAsync(d_out, 0, sizeof(float), stream);
        chamfer_min_kernel<<<NBLK, TPB, 0, stream>>>(pc1, pc2, part);
        chamfer_reduce_kernel<<<NI / 256, 256, 0, stream>>>(part, out);
    }
}

// Round 6
// 69.318 us; speedup vs baseline: 3.6384x; 3.6384x over previous
//
#include <hip/hip_runtime.h>
#include <math.h>

#define BB 4
#define NN 4096
#define TPB 256            // 4 waves per block
#define IPT 4              // i-points per thread
#define IBLK (TPB * IPT)   // 1024 i-points per block
#define ITILES (NN / IBLK) // 4
#define JCHUNK 256
#define NJC (NN / JCHUNK)  // 16
#define NBLK (BB * 2 * ITILES * NJC)       // 512
#define NI (2 * BB * NN)   // 32768 total (b,dir,i) slots
#define PART_BYTES ((size_t)NJC * NI * 4)  // 2 MB

// ---------------- fallback path: init mins to +inf ----------------
__global__ void init_mins_kernel(unsigned int* mins, float* out) {
    int idx = blockIdx.x * blockDim.x + threadIdx.x;
    if (idx < NI) mins[idx] = 0x7F800000u;  // +inf
    if (idx == 0) out[0] = 0.f;
}

// ---------------- main pair-distance kernel ----------------
// d^2(i,j) = |p_i|^2 - 2*(p_i.q_j - 0.5|q_j|^2).  Track max over j of
// s_j = p.q + w  (w = -0.5|q|^2 precomputed into the LDS float4's .w):
// inner loop is 3 fma + 1 max per pair.
template <bool USE_ATOMIC>
__global__ __launch_bounds__(TPB) void chamfer_min_kernel(
    const float* __restrict__ pc1, const float* __restrict__ pc2,
    float* __restrict__ part, unsigned int* __restrict__ mins,
    float* __restrict__ out) {
    // Zero the output accumulator here (stream-ordered before the reduce
    // kernel's atomicAdds; kernel boundary makes it visible) — this replaces
    // a separate hipMemsetAsync graph node.
    if (!USE_ATOMIC && blockIdx.x == 0 && threadIdx.x == 0) out[0] = 0.f;

    // blockIdx.x bits: [jc:4][itile:2][dir:1][b:2]
    int bid = blockIdx.x;
    int jc    = bid & (NJC - 1);    bid >>= 4;
    int itile = bid & (ITILES - 1); bid >>= 2;
    int dir   = bid & 1;            bid >>= 1;
    int b     = bid;

    const float* selfc  = (dir == 0) ? pc1 : pc2;
    const float* otherc = (dir == 0) ? pc2 : pc1;

    // Stage JCHUNK j-points as (x, y, z, -0.5*|q|^2) in LDS (4 KB).
    __shared__ float4 sj[JCHUNK];
    const float4* src4 =
        (const float4*)(otherc + (size_t)b * NN * 3 + (size_t)jc * JCHUNK * 3);
    if (threadIdx.x < JCHUNK / 4) {
        int t = threadIdx.x;
        float4 f0 = src4[3 * t + 0];
        float4 f1 = src4[3 * t + 1];
        float4 f2 = src4[3 * t + 2];
        float x0 = f0.x, y0 = f0.y, z0 = f0.z;
        float x1 = f0.w, y1 = f1.x, z1 = f1.y;
        float x2 = f1.z, y2 = f1.w, z2 = f2.x;
        float x3 = f2.y, y3 = f2.z, z3 = f2.w;
        sj[4 * t + 0] = make_float4(x0, y0, z0, -0.5f * (x0 * x0 + y0 * y0 + z0 * z0));
        sj[4 * t + 1] = make_float4(x1, y1, z1, -0.5f * (x1 * x1 + y1 * y1 + z1 * z1));
        sj[4 * t + 2] = make_float4(x2, y2, z2, -0.5f * (x2 * x2 + y2 * y2 + z2 * z2));
        sj[4 * t + 3] = make_float4(x3, y3, z3, -0.5f * (x3 * x3 + y3 * y3 + z3 * z3));
    }

    // Issue this thread's i-point loads before the barrier (overlap staging).
    float px[IPT], py[IPT], pz[IPT], pp[IPT], m[IPT];
    const float* pbase = selfc + (size_t)b * NN * 3 +
                         (size_t)(itile * IBLK + threadIdx.x) * 3;
#pragma unroll
    for (int r = 0; r < IPT; ++r) {
        const float* p = pbase + (size_t)r * TPB * 3;
        px[r] = p[0]; py[r] = p[1]; pz[r] = p[2];
        pp[r] = px[r] * px[r] + py[r] * py[r] + pz[r] * pz[r];
        m[r] = -INFINITY;
    }
    __syncthreads();

    // All lanes read the same LDS address -> broadcast, zero bank conflicts.
#pragma unroll 4
    for (int j = 0; j < JCHUNK; ++j) {
        float4 q = sj[j];
#pragma unroll
        for (int r = 0; r < IPT; ++r) {
            float t = fmaf(px[r], q.x, q.w);
            t = fmaf(py[r], q.y, t);
            t = fmaf(pz[r], q.z, t);
            m[r] = fmaxf(m[r], t);
        }
    }

    int slot0 = (b * 2 + dir) * NN + itile * IBLK + threadIdx.x;
#pragma unroll
    for (int r = 0; r < IPT; ++r) {
        float d2 = fmaxf(0.f, fmaf(-2.f, m[r], pp[r]));
        int slot = slot0 + r * TPB;
        if (USE_ATOMIC) {
            atomicMin(&mins[slot], __float_as_uint(d2));
        } else {
            part[(size_t)jc * NI + slot] = d2;  // coalesced
        }
    }
}

// ---------------- final reduce: min over j-chunks, sqrt, sum ----------------
template <bool USE_ATOMIC>
__global__ __launch_bounds__(256) void chamfer_reduce_kernel(
    const float* __restrict__ part, const unsigned int* __restrict__ mins,
    float* __restrict__ out) {
    int g = blockIdx.x * 256 + threadIdx.x;  // 128 blocks * 256 = 32768 = NI
    float m;
    if (USE_ATOMIC) {
        m = __uint_as_float(mins[g]);
    } else {
        m = part[g];
#pragma unroll
        for (int c = 1; c < NJC; ++c) m = fminf(m, part[(size_t)c * NI + g]);
    }
    float s = sqrtf(fmaxf(m, 0.f));
    // wave (64-lane) reduce
    for (int off = 32; off > 0; off >>= 1) s += __shfl_down(s, off, 64);
    __shared__ float wsum[4];
    int wave = threadIdx.x >> 6;
    if ((threadIdx.x & 63) == 0) wsum[wave] = s;
    __syncthreads();
    if (threadIdx.x == 0) {
        float tot = wsum[0] + wsum[1] + wsum[2] + wsum[3];
        // mean over B of (sum_minA + sum_minB)/(2N)  ==  total / (2*B*N)
        atomicAdd(out, tot * (1.0f / (float)NI));
    }
}

extern "C" void kernel_launch(void* const* d_in, const int* in_sizes, int n_in,
                              void* d_out, int out_size, void* d_ws, size_t ws_size,
                              hipStream_t stream) {
    const float* pc1 = (const float*)d_in[0];
    const float* pc2 = (const float*)d_in[1];
    float* out = (float*)d_out;

    if (ws_size >= PART_BYTES) {
        // 2-node path: min kernel zeroes out[0]; reduce atomicAdds partials.
        float* part = (float*)d_ws;
        chamfer_min_kernel<false><<<NBLK, TPB, 0, stream>>>(pc1, pc2, part,
                                                            nullptr, out);
        chamfer_reduce_kernel<false><<<NI / 256, 256, 0, stream>>>(part, nullptr,
                                                                   out);
    } else {
        unsigned int* mins = (unsigned int*)d_ws;
        init_mins_kernel<<<NI / 256, 256, 0, stream>>>(mins, out);
        chamfer_min_kernel<true><<<NBLK, TPB, 0, stream>>>(pc1, pc2, nullptr,
                                                           mins, out);
        chamfer_reduce_kernel<true><<<NI / 256, 256, 0, stream>>>(nullptr, mins,
                                                                  out);
    }
}